// Round 1
// baseline (530.395 us; speedup 1.0000x reference)
//
#include <hip/hip_runtime.h>
#include <hip/hip_bf16.h>

typedef __hip_bfloat16 bf16;

// ---------------------------------------------------------------------------
// CROMAMBA fused pipeline, MI355X.
// Shapes: B=128, DI=64, K=4, N=24, R=24, L=256 (16x16).
// ws layout (120 MiB):
//   xT  bf16 [2][128][256][64]      x transposed to (l,d), scan-u source
//   dts bf16 [2][128][4][256][64]   softplus(dt_proj + dt_bias)  (pre-activated)
//   Bs  f32  [2][128][4][256][24]
//   Cs  f32  [2][128][4][256][24]
//   ys  bf16 [2][128][4][256][64]   scan output (+ u*D), (l,d) layout
// ---------------------------------------------------------------------------

struct KParams {
  const float* in[30];
  bf16* xT;
  bf16* dts;
  float* Bs;
  float* Cs;
  bf16* ys;
  float* out;
};

__device__ __forceinline__ float silu_(float x) { return x / (1.f + __expf(-x)); }
__device__ __forceinline__ float softplus_(float x) { return x > 15.f ? x : log1pf(__expf(x)); }
__device__ __forceinline__ int t16_(int l) { return ((l & 15) << 4) | (l >> 4); }
// scan-source index: k0: l, k1: T(l), k2: 255-l, k3: T(255-l)
__device__ __forceinline__ int srcidx_(int k, int l) {
  int a = (k & 2) ? 255 - l : l;
  return (k & 1) ? t16_(a) : a;
}
__device__ __forceinline__ float bflo_(unsigned u) { return __uint_as_float(u << 16); }
__device__ __forceinline__ float bfhi_(unsigned u) { return __uint_as_float(u & 0xffff0000u); }

// ===========================================================================
// KA: per (branch,b): in-LDS front conv chain + direction projections.
// grid 256 = br*128+b, block 512.
// ===========================================================================
__global__ __launch_bounds__(512) void ka_front(KParams P) {
  const int bid = blockIdx.x;
  const int br = bid >> 7;
  const int tid = threadIdx.x;
  const int pb = 2 + 13 * br;
  const float* __restrict__ xin = P.in[br] + ((bid & 127) << 14);

  __shared__ float R0[16640];   // x_in -> x_ (padded 65) -> stage buffers
  __shared__ float R1[16896];   // re_pad (4x64x66, zero borders) -> xT (256x65)

  // ph1: x_in -> R0 (coalesced), zero R1 (conv SAME borders)
  for (int i = tid; i < 4096; i += 512) ((float4*)R0)[i] = ((const float4*)xin)[i];
  for (int i = tid; i < 16896; i += 512) R1[i] = 0.f;
  __syncthreads();

  // ph2: pixel-shuffle rearrange: re[i][y][x] = x_in[y>>2][x>>2][i*16+(y&3)*4+(x&3)]
  for (int idx = tid; idx < 16384; idx += 512) {
    int i = idx >> 12, y = (idx >> 6) & 63, x = idx & 63;
    R1[i * 4224 + y * 66 + x + 1] =
        R0[((y >> 2) << 10) + ((x >> 2) << 6) + (i << 4) + ((y & 3) << 2) + (x & 3)];
  }
  __syncthreads();

  // ph3: depthwise 3x3 SAME + bias + SiLU -> R0[i*4160 + y*65 + x]
  {
    const float* __restrict__ cw = P.in[pb + 1];
    const float* __restrict__ cb = P.in[pb + 2];
    const int i = tid >> 7, y = (tid >> 1) & 63, xh = (tid & 1) << 5;
    const float w0 = cw[i * 9 + 0], w1 = cw[i * 9 + 1], w2 = cw[i * 9 + 2];
    const float w3 = cw[i * 9 + 3], w4 = cw[i * 9 + 4], w5 = cw[i * 9 + 5];
    const float w6 = cw[i * 9 + 6], w7 = cw[i * 9 + 7], w8 = cw[i * 9 + 8];
    const float bias = cb[i];
    const float* rp = R1 + i * 4224;
    float* op = R0 + i * 4160 + y * 65;
    for (int x = xh; x < xh + 32; ++x) {
      float acc = bias;
      if (y > 0) { const float* r = rp + (y - 1) * 66 + x; acc += w0 * r[0] + w1 * r[1] + w2 * r[2]; }
      { const float* r = rp + y * 66 + x; acc += w3 * r[0] + w4 * r[1] + w5 * r[2]; }
      if (y < 63) { const float* r = rp + (y + 1) * 66 + x; acc += w6 * r[0] + w7 * r[1] + w8 * r[2]; }
      op[x] = silu_(acc);
    }
  }
  __syncthreads();

  // ph4: 4x4/4 patch conv + bias + BN(rm=0,rv=1) -> R1 transposed xT[p*65+o]
  {
    const float* __restrict__ pw = P.in[pb + 3];
    const float* __restrict__ pbb = P.in[pb + 4];
    const float* __restrict__ bng = P.in[pb + 5];
    const float* __restrict__ bnb = P.in[pb + 6];
    const float bnf = rsqrtf(1.f + 1e-5f);
    const int p = tid & 255, oh2 = tid >> 8;
    const int rb = (p >> 4) * 4 * 65 + (p & 15) * 4;
    float win[64];
#pragma unroll
    for (int i = 0; i < 4; ++i)
#pragma unroll
      for (int kh = 0; kh < 4; ++kh)
#pragma unroll
        for (int kw = 0; kw < 4; ++kw)
          win[i * 16 + kh * 4 + kw] = R0[i * 4160 + rb + kh * 65 + kw];
    for (int oi = 0; oi < 32; ++oi) {
      const int o = __builtin_amdgcn_readfirstlane(oh2 * 32 + oi);
      const float* wr = pw + o * 64;
      float acc = 0.f;
#pragma unroll
      for (int j = 0; j < 64; ++j) acc = fmaf(win[j], wr[j], acc);
      R1[p * 65 + o] = fmaf(acc + pbb[o], bng[o] * bnf, bnb[o]);
    }
  }
  __syncthreads();

  // ph5: flush xT (bf16, coalesced)
  {
    bf16* __restrict__ xtg = P.xT + (bid << 14);
    for (int idx = tid; idx < 16384; idx += 512)
      xtg[idx] = __float2bfloat16(R1[(idx >> 6) * 65 + (idx & 63)]);
  }

  // ph6: per-direction projections. thread = (l, half); accumulator-array form.
  {
    const float* __restrict__ wp = P.in[pb + 7];    // (4,72,64)
    const float* __restrict__ wdt = P.in[pb + 8];   // (4,64,24)
    const float* __restrict__ dtb = P.in[pb + 9];   // (4,64)
    const int l = tid & 255, h2 = tid >> 8;
    for (int k = 0; k < 4; ++k) {
      const int sl = srcidx_(k, l);
      const float* xc = R1 + sl * 65;
      float acc[48];
      if (h2 == 0) {
        // c = 0..23 (dt_rank inputs), then dt = Wdt @ r24, softplus(+bias) -> stage
#pragma unroll
        for (int c = 0; c < 24; ++c) acc[c] = 0.f;
        const float* wpk = wp + k * 72 * 64;
        for (int d = 0; d < 64; ++d) {
          const float xv = xc[d];
#pragma unroll
          for (int c = 0; c < 24; ++c) acc[c] = fmaf(xv, wpk[c * 64 + d], acc[c]);
        }
        const float* wdk = wdt + k * 64 * 24;
        const float* dbk = dtb + k * 64;
        for (int d = 0; d < 64; ++d) {
          const float* wr = wdk + d * 24;
          float s = dbk[d];
#pragma unroll
          for (int r = 0; r < 24; ++r) s = fmaf(acc[r], wr[r], s);
          R0[l * 65 + d] = softplus_(s);
        }
      } else {
        // c = 24..71 (B then C)
#pragma unroll
        for (int c = 0; c < 48; ++c) acc[c] = 0.f;
        const float* wpk = wp + (k * 72 + 24) * 64;
        for (int d = 0; d < 64; ++d) {
          const float xv = xc[d];
#pragma unroll
          for (int c = 0; c < 48; ++c) acc[c] = fmaf(xv, wpk[c * 64 + d], acc[c]);
        }
      }
      __syncthreads();
      { // flush delta (bf16, coalesced)
        bf16* __restrict__ dg = P.dts + ((bid << 2) + k) * 16384;
        for (int idx = tid; idx < 16384; idx += 512)
          dg[idx] = __float2bfloat16(R0[(idx >> 6) * 65 + (idx & 63)]);
      }
      __syncthreads();
      if (h2 == 1) {
#pragma unroll
        for (int c = 0; c < 48; ++c) R0[l * 49 + c] = acc[c];
      }
      __syncthreads();
      { // flush B, C (f32, coalesced)
        float* __restrict__ bg = P.Bs + ((bid << 2) + k) * 6144;
        float* __restrict__ cg = P.Cs + ((bid << 2) + k) * 6144;
        for (int idx = tid; idx < 6144; idx += 512) {
          const int ll = idx / 24, n = idx - ll * 24;
          bg[idx] = R0[ll * 49 + n];
          cg[idx] = R0[ll * 49 + 24 + n];
        }
      }
      __syncthreads();
    }
  }
}

// ===========================================================================
// KB: selective scan. grid 1024 = m*512 + b*4 + k, block 128 (2 waves:
// lane=d, wave-half nh owns states n in [nh*12, nh*12+12)).
// Cross-modal: modality m's u = xs(branch m); all params from branch 1-m.
// ===========================================================================
__global__ __launch_bounds__(128) void kb_scan(KParams P) {
  const int bid = blockIdx.x;
  const int m = bid >> 9, b = (bid >> 2) & 127, k = bid & 3;
  const int pbr = 1 - m;
  const int tid = threadIdx.x;
  const int d = tid & 63, nh = tid >> 6;
  const int pbase = 2 + 13 * pbr;
  const float* __restrict__ alog = P.in[pbase + 10];
  const float* __restrict__ dsv = P.in[pbase + 11];
  float a[12];
#pragma unroll
  for (int j = 0; j < 12; ++j) a[j] = -__expf(alog[(k * 64 + d) * 24 + nh * 12 + j]);
  const float Dv = dsv[k * 64 + d];
  const int pslice = ((pbr * 128 + b) << 2) + k;
  const int mslice = ((m * 128 + b) << 2) + k;
  const bf16* __restrict__ dg = P.dts + pslice * 16384;
  const float4* __restrict__ Bg4 = (const float4*)(P.Bs + pslice * 6144) + nh * 3;
  const float4* __restrict__ Cg4 = (const float4*)(P.Cs + pslice * 6144) + nh * 3;
  const bf16* __restrict__ ug = P.xT + ((m * 128 + b) << 14);
  bf16* __restrict__ yg = P.ys + mslice * 16384;
  __shared__ float ybuf[2][64];
  float h[12];
#pragma unroll
  for (int j = 0; j < 12; ++j) h[j] = 0.f;
  for (int l = 0; l < 256; ++l) {
    const int sl = srcidx_(k, l);
    const float uv = __bfloat162float(ug[(sl << 6) + d]);
    const float delta = __bfloat162float(dg[(l << 6) + d]);  // softplus pre-applied
    float Bv[12], Cv[12];
    *(float4*)&Bv[0] = Bg4[l * 6 + 0];
    *(float4*)&Bv[4] = Bg4[l * 6 + 1];
    *(float4*)&Bv[8] = Bg4[l * 6 + 2];
    *(float4*)&Cv[0] = Cg4[l * 6 + 0];
    *(float4*)&Cv[4] = Cg4[l * 6 + 1];
    *(float4*)&Cv[8] = Cg4[l * 6 + 2];
    const float du = delta * uv;
    float yp = 0.f;
#pragma unroll
    for (int j = 0; j < 12; ++j) {
      const float e = __expf(delta * a[j]);
      h[j] = fmaf(e, h[j], du * Bv[j]);
      yp = fmaf(h[j], Cv[j], yp);
    }
    if (nh) ybuf[l & 1][d] = yp;
    __syncthreads();
    if (!nh) yg[(l << 6) + d] = __float2bfloat16(yp + ybuf[l & 1][d] + uv * Dv);
  }
}

// ===========================================================================
// KC: cross-merge + LayerNorm + z-gate (recomputed) + out_proj.
// grid 256 = m*128+b, block 256 (thread = pixel p, hw order).
// ===========================================================================
__global__ __launch_bounds__(256) void kc_finish(KParams P) {
  const int bid = blockIdx.x;
  const int m = bid >> 7;
  const int p = threadIdx.x;
  const int pbm = 2 + 13 * m;
  const bf16* __restrict__ yb = P.ys + (bid << 2) * 16384;
  const int tp = t16_(p);
  const unsigned* __restrict__ r0 = (const unsigned*)(yb + (p << 6));
  const unsigned* __restrict__ r1 = (const unsigned*)(yb + 16384 + (tp << 6));
  const unsigned* __restrict__ r2 = (const unsigned*)(yb + 2 * 16384 + ((255 - p) << 6));
  const unsigned* __restrict__ r3 = (const unsigned*)(yb + 3 * 16384 + ((255 - tp) << 6));
  float ym[64];
  float mu = 0.f;
#pragma unroll
  for (int j = 0; j < 32; ++j) {
    const unsigned a0 = r0[j], a1 = r1[j], a2 = r2[j], a3 = r3[j];
    const float e0 = bflo_(a0) + bflo_(a1) + bflo_(a2) + bflo_(a3);
    const float e1 = bfhi_(a0) + bfhi_(a1) + bfhi_(a2) + bfhi_(a3);
    ym[2 * j] = e0; ym[2 * j + 1] = e1;
    mu += e0 + e1;
  }
  mu *= (1.f / 64.f);
  float var = 0.f;
#pragma unroll
  for (int dd = 0; dd < 64; ++dd) { const float t = ym[dd] - mu; var = fmaf(t, t, var); }
  const float rstd = rsqrtf(var * (1.f / 64.f) + 1e-5f);

  // z = silu(x_in @ Win^T), accumulator-array over output channel
  const float* __restrict__ xin = P.in[m] + (((bid & 127) << 8) + p) * 64;
  const float* __restrict__ win = P.in[pbm];
  float zacc[64];
#pragma unroll
  for (int dd = 0; dd < 64; ++dd) zacc[dd] = 0.f;
  for (int c = 0; c < 64; ++c) {
    const float xv = xin[c];
#pragma unroll
    for (int dd = 0; dd < 64; ++dd) zacc[dd] = fmaf(xv, win[dd * 64 + c], zacc[dd]);
  }
  const float* __restrict__ lng = P.in[28];
  const float* __restrict__ lnb = P.in[29];
  __shared__ float vbuf[16640];
  __shared__ float obuf[16640];
#pragma unroll
  for (int dd = 0; dd < 64; ++dd) {
    const float yn = fmaf((ym[dd] - mu) * rstd, lng[dd], lnb[dd]);
    vbuf[p * 65 + dd] = yn * silu_(zacc[dd]);  // per-thread bounce for dynamic idx
  }
  const float* __restrict__ wout = P.in[pbm + 12];
  float oacc[64];
#pragma unroll
  for (int o = 0; o < 64; ++o) oacc[o] = 0.f;
  for (int dd = 0; dd < 64; ++dd) {
    const float vv = vbuf[p * 65 + dd];
#pragma unroll
    for (int o = 0; o < 64; ++o) oacc[o] = fmaf(vv, wout[o * 64 + dd], oacc[o]);
  }
#pragma unroll
  for (int o = 0; o < 64; ++o) obuf[p * 65 + o] = oacc[o];
  __syncthreads();
  float* __restrict__ og = P.out + (bid << 14);
  for (int idx = p; idx < 4096; idx += 256) {
    const int pp = idx >> 4, q = (idx & 15) << 2;
    const float* ob = obuf + pp * 65 + q;
    ((float4*)og)[idx] = make_float4(ob[0], ob[1], ob[2], ob[3]);
  }
}

// ===========================================================================
extern "C" void kernel_launch(void* const* d_in, const int* in_sizes, int n_in,
                              void* d_out, int out_size, void* d_ws, size_t ws_size,
                              hipStream_t stream) {
  (void)in_sizes; (void)out_size;
  if (n_in < 30) return;
  if (ws_size < 125829120ull) return;  // clean fail instead of OOB scribble
  KParams P;
  for (int i = 0; i < 30; ++i) P.in[i] = (const float*)d_in[i];
  char* w = (char*)d_ws;
  P.xT  = (bf16*)(w);
  P.dts = (bf16*)(w + 8388608);
  P.Bs  = (float*)(w + 41943040);
  P.Cs  = (float*)(w + 67108864);
  P.ys  = (bf16*)(w + 92274688);
  P.out = (float*)d_out;
  hipLaunchKernelGGL(ka_front, dim3(256), dim3(512), 0, stream, P);
  hipLaunchKernelGGL(kb_scan, dim3(1024), dim3(128), 0, stream, P);
  hipLaunchKernelGGL(kc_finish, dim3(256), dim3(256), 0, stream, P);
}

// Round 2
// 415.236 us; speedup vs baseline: 1.2773x; 1.2773x over previous
//
#include <hip/hip_runtime.h>
#include <hip/hip_bf16.h>

typedef __hip_bfloat16 bf16;
typedef unsigned int uint;
typedef unsigned short ushort;

// ---------------------------------------------------------------------------
// CROMAMBA fused pipeline, MI355X.  B=128, DI=64, K=4, N=24, R=24, L=256.
// All cross-scan permutations are involutions; projections are computed in
// NATURAL hw order (x_dbl[k,c,t] = Y_k[c][srcidx(k,t)]), the scan kernel
// applies srcidx to its (wave-uniform) row reads and writes ys back in
// natural order, so the merge is 4 plain row reads.
// ws layout (exactly 120 MiB):
//   xld bf16 [2][128][256][64]      @ 0        (8 MB)   x, (l,d), natural
//   dts bf16 [2][128][4][256][64]   @ 8 MB     (32 MB)  softplus(dt)  natural
//   Bs  f32  [2][128][4][256][24]   @ 40 MB    (24 MB)  natural
//   Cs  f32  [2][128][4][256][24]   @ 64 MB    (24 MB)  natural
//   ys  bf16 [2][128][4][256][64]   @ 88 MB    (32 MB)  natural (merged order)
// ---------------------------------------------------------------------------

struct KParams {
  const float* in[30];
  bf16* xld;
  bf16* dts;
  float* Bs;
  float* Cs;
  bf16* ys;
  float* out;
};

__device__ __forceinline__ float silu_(float x) { return x / (1.f + __expf(-x)); }
__device__ __forceinline__ float softplus_(float x) { return x > 15.f ? x : log1pf(__expf(x)); }
__device__ __forceinline__ int t16_(int l) { return ((l & 15) << 4) | (l >> 4); }
// scan-source index (involution): k0: l, k1: T(l), k2: 255-l, k3: T(255-l)
__device__ __forceinline__ int srcidx_(int k, int l) {
  int a = (k & 2) ? 255 - l : l;
  return (k & 1) ? t16_(a) : a;
}
__device__ __forceinline__ float bflo_(uint u) { return __uint_as_float(u << 16); }
__device__ __forceinline__ float bfhi_(uint u) { return __uint_as_float(u & 0xffff0000u); }
__device__ __forceinline__ uint packbf_(float a, float b) {
  bf16 x = __float2bfloat16(a), y = __float2bfloat16(b);
  return (uint)__builtin_bit_cast(unsigned short, x) |
         ((uint)__builtin_bit_cast(unsigned short, y) << 16);
}

// ===========================================================================
// KA: per (branch,b): in-LDS front conv chain. grid 256 = br*128+b, block 512.
// ===========================================================================
__global__ __launch_bounds__(512) void ka_front(KParams P) {
  const int bid = blockIdx.x;
  const int br = bid >> 7;
  const int tid = threadIdx.x;
  const int pb = 2 + 13 * br;
  const float* __restrict__ xin = P.in[br] + ((bid & 127) << 14);

  __shared__ float R0[16640];   // x_in -> x_ (padded 65)
  __shared__ float R1[16896];   // re_pad (4x64x66, zero borders) -> xT (256x65)

  // ph1: x_in -> R0 (coalesced), zero R1 (conv SAME borders)
  for (int i = tid; i < 4096; i += 512) ((float4*)R0)[i] = ((const float4*)xin)[i];
  for (int i = tid; i < 16896; i += 512) R1[i] = 0.f;
  __syncthreads();

  // ph2: pixel-shuffle rearrange
  for (int idx = tid; idx < 16384; idx += 512) {
    int i = idx >> 12, y = (idx >> 6) & 63, x = idx & 63;
    R1[i * 4224 + y * 66 + x + 1] =
        R0[((y >> 2) << 10) + ((x >> 2) << 6) + (i << 4) + ((y & 3) << 2) + (x & 3)];
  }
  __syncthreads();

  // ph3: depthwise 3x3 SAME + bias + SiLU -> R0[i*4160 + y*65 + x]
  {
    const float* __restrict__ cw = P.in[pb + 1];
    const float* __restrict__ cb = P.in[pb + 2];
    const int i = tid >> 7, y = (tid >> 1) & 63, xh = (tid & 1) << 5;
    const float w0 = cw[i * 9 + 0], w1 = cw[i * 9 + 1], w2 = cw[i * 9 + 2];
    const float w3 = cw[i * 9 + 3], w4 = cw[i * 9 + 4], w5 = cw[i * 9 + 5];
    const float w6 = cw[i * 9 + 6], w7 = cw[i * 9 + 7], w8 = cw[i * 9 + 8];
    const float bias = cb[i];
    const float* rp = R1 + i * 4224;
    float* op = R0 + i * 4160 + y * 65;
    for (int x = xh; x < xh + 32; ++x) {
      float acc = bias;
      if (y > 0) { const float* r = rp + (y - 1) * 66 + x; acc += w0 * r[0] + w1 * r[1] + w2 * r[2]; }
      { const float* r = rp + y * 66 + x; acc += w3 * r[0] + w4 * r[1] + w5 * r[2]; }
      if (y < 63) { const float* r = rp + (y + 1) * 66 + x; acc += w6 * r[0] + w7 * r[1] + w8 * r[2]; }
      op[x] = silu_(acc);
    }
  }
  __syncthreads();

  // ph4: 4x4/4 patch conv + bias + BN -> R1 transposed xT[p*65+o]
  {
    const float* __restrict__ pw = P.in[pb + 3];
    const float* __restrict__ pbb = P.in[pb + 4];
    const float* __restrict__ bng = P.in[pb + 5];
    const float* __restrict__ bnb = P.in[pb + 6];
    const float bnf = rsqrtf(1.f + 1e-5f);
    const int p = tid & 255, oh2 = tid >> 8;
    const int rb = (p >> 4) * 4 * 65 + (p & 15) * 4;
    float win[64];
#pragma unroll
    for (int i = 0; i < 4; ++i)
#pragma unroll
      for (int kh = 0; kh < 4; ++kh)
#pragma unroll
        for (int kw = 0; kw < 4; ++kw)
          win[i * 16 + kh * 4 + kw] = R0[i * 4160 + rb + kh * 65 + kw];
    for (int oi = 0; oi < 32; ++oi) {
      const int o = __builtin_amdgcn_readfirstlane(oh2 * 32 + oi);
      const float* wr = pw + o * 64;
      float acc = 0.f;
#pragma unroll
      for (int j = 0; j < 64; ++j) acc = fmaf(win[j], wr[j], acc);
      R1[p * 65 + o] = fmaf(acc + pbb[o], bng[o] * bnf, bnb[o]);
    }
  }
  __syncthreads();

  // ph5: flush xld (bf16 packed u32, coalesced)
  {
    uint* __restrict__ xg = (uint*)(P.xld + (bid << 14));
    for (int idx = tid; idx < 8192; idx += 512) {
      const int l = idx >> 5, d2 = (idx & 31) << 1;
      xg[idx] = packbf_(R1[l * 65 + d2], R1[l * 65 + d2 + 1]);
    }
  }
}

// ===========================================================================
// KP: direction projections (natural order). grid 1024 = (br,b,k), block 256.
// Register-blocked GEMM: thread (g=wave 0..3 -> 18 c's, l4=lane -> 4 l's),
// weights via wave-uniform s_load, x via ds_read_b64 from [d][l] LDS tile.
// ===========================================================================
__global__ __launch_bounds__(256) void kp_proj(KParams P) {
  const int bid = blockIdx.x;
  const int br = bid >> 9, b = (bid >> 2) & 127, k = bid & 3;
  const int tid = threadIdx.x;
  const int pb = 2 + 13 * br;
  __shared__ float smem[18720];            // 74880 B -> 2 blocks/CU
  ushort* __restrict__ Xs = (ushort*)smem; // [64][256] bf16 (first 32 KB)
  float* __restrict__ BC = smem;           // [48][260] f32 (aliases Xs, used later)
  float* __restrict__ Ydt = smem + 12480;  // [24][260] f32 @ 49920 B
  uint* __restrict__ dtst = (uint*)smem;   // [256][33] u32 (aliases BC, last phase)

  // stage-transpose X: global [l][64] -> LDS [64][256]
  {
    const uint* __restrict__ xg = (const uint*)(P.xld + ((br * 128 + b) << 14));
    const int base = tid * 32;
#pragma unroll
    for (int j = 0; j < 32; ++j) {
      const uint v = xg[base + j];
      Xs[(2 * j) * 256 + tid] = (ushort)(v & 0xffffu);
      Xs[(2 * j + 1) * 256 + tid] = (ushort)(v >> 16);
    }
  }
  __syncthreads();

  const int l4 = tid & 63, g = tid >> 6;
  float acc[72];
#pragma unroll
  for (int c = 0; c < 72; ++c) acc[c] = 0.f;
  {
    const float* __restrict__ wpk = P.in[pb + 7] + k * 4608 + g * 18 * 64;
#pragma unroll 2
    for (int dd = 0; dd < 64; ++dd) {
      const uint2 xv2 = *(const uint2*)(Xs + dd * 256 + 4 * l4);
      const float x0 = bflo_(xv2.x), x1 = bfhi_(xv2.x);
      const float x2 = bflo_(xv2.y), x3 = bfhi_(xv2.y);
#pragma unroll
      for (int cc = 0; cc < 18; ++cc) {
        const float w = wpk[cc * 64 + dd];
        acc[cc * 4 + 0] = fmaf(w, x0, acc[cc * 4 + 0]);
        acc[cc * 4 + 1] = fmaf(w, x1, acc[cc * 4 + 1]);
        acc[cc * 4 + 2] = fmaf(w, x2, acc[cc * 4 + 2]);
        acc[cc * 4 + 3] = fmaf(w, x3, acc[cc * 4 + 3]);
      }
    }
  }
  __syncthreads();  // all X reads done before BC overwrites the region

  // scatter results: c<24 -> Ydt stage, c>=24 -> BC stage (B rows then C rows)
#pragma unroll
  for (int cc = 0; cc < 18; ++cc) {
    const int c = g * 18 + cc;
    float* dst = (c < 24 ? Ydt + c * 260 : BC + (c - 24) * 260) + 4 * l4;
    *(float4*)dst = make_float4(acc[cc * 4 + 0], acc[cc * 4 + 1], acc[cc * 4 + 2], acc[cc * 4 + 3]);
  }
  __syncthreads();

  // flush B, C -> [l][24] f32, coalesced
  {
    const int slice = ((br * 128 + b) << 2) + k;
    float* __restrict__ Bg = P.Bs + slice * 6144;
    float* __restrict__ Cg = P.Cs + slice * 6144;
    for (int idx = tid; idx < 6144; idx += 256) {
      const int l = idx / 24, n = idx - 24 * l;
      Bg[idx] = BC[n * 260 + l];
      Cg[idx] = BC[(24 + n) * 260 + l];
    }
  }
  __syncthreads();

  // dt GEMM + bias + softplus, thread = l; weights via contiguous s_load rows
  {
    float r24[24];
#pragma unroll
    for (int r = 0; r < 24; ++r) r24[r] = Ydt[r * 260 + tid];
    const float* __restrict__ wdk = P.in[pb + 8] + k * 1536;
    const float* __restrict__ dbk = P.in[pb + 9] + k * 64;
#pragma unroll 2
    for (int d2 = 0; d2 < 32; ++d2) {
      float s0 = dbk[2 * d2], s1 = dbk[2 * d2 + 1];
      const float* w0 = wdk + (2 * d2) * 24;
#pragma unroll
      for (int r = 0; r < 24; ++r) {
        s0 = fmaf(r24[r], w0[r], s0);
        s1 = fmaf(r24[r], w0[24 + r], s1);
      }
      dtst[tid * 33 + d2] = packbf_(softplus_(s0), softplus_(s1));
    }
  }
  __syncthreads();

  // flush dts [l][64] bf16, coalesced
  {
    uint* __restrict__ dgo = (uint*)(P.dts + (((br * 128 + b) << 2) + k) * 16384);
    for (int idx = tid; idx < 8192; idx += 256)
      dgo[idx] = dtst[(idx >> 5) * 33 + (idx & 31)];
  }
}

// ===========================================================================
// KB: selective scan. grid 1024 = m*512+b*4+k, block 64 (ONE wave, lane = d,
// all 24 states in-lane -> no barriers). 2-deep software prefetch pipeline.
// Cross-modal: modality m's u = branch m; dt/A/B/C/D from branch 1-m.
// ===========================================================================
__global__ __launch_bounds__(64) void kb_scan(KParams P) {
  const int bid = blockIdx.x;
  const int m = bid >> 9, b = (bid >> 2) & 127, k = bid & 3;
  const int pbr = 1 - m, pbase = 2 + 13 * pbr;
  const int d = threadIdx.x;
  const float* __restrict__ alog = P.in[pbase + 10];
  const float* __restrict__ dsv = P.in[pbase + 11];
  float a[24];
#pragma unroll
  for (int j = 0; j < 24; ++j) a[j] = -__expf(alog[(k * 64 + d) * 24 + j]);
  const float Dv = dsv[k * 64 + d];
  const int ps = ((pbr * 128 + b) << 2) + k;
  const bf16* __restrict__ dg = P.dts + ps * 16384;
  const float* __restrict__ Bg = P.Bs + ps * 6144;
  const float* __restrict__ Cg = P.Cs + ps * 6144;
  const bf16* __restrict__ ug = P.xld + ((m * 128 + b) << 14);
  bf16* __restrict__ yg = P.ys + (((m * 128 + b) << 2) + k) * 16384;

  float h[24];
#pragma unroll
  for (int j = 0; j < 24; ++j) h[j] = 0.f;
  float uA, dA, BA[24], CA[24], uB, dB, BB[24], CB[24];

#define KB_LOAD(t, u_, dl_, Bv_, Cv_)                                   \
  {                                                                     \
    const int tc_ = (t) > 255 ? 255 : (t);                              \
    const int sl_ = srcidx_(k, tc_);                                    \
    u_ = __bfloat162float(ug[(sl_ << 6) + d]);                          \
    dl_ = __bfloat162float(dg[(sl_ << 6) + d]);                         \
    const float4* bp_ = (const float4*)(Bg + sl_ * 24);                 \
    const float4* cp_ = (const float4*)(Cg + sl_ * 24);                 \
    _Pragma("unroll") for (int q = 0; q < 6; ++q) {                     \
      *(float4*)&Bv_[4 * q] = bp_[q];                                   \
      *(float4*)&Cv_[4 * q] = cp_[q];                                   \
    }                                                                   \
  }

#define KB_STEP(t, u_, dl_, Bv_, Cv_)                                   \
  {                                                                     \
    const int sl_ = srcidx_(k, (t));                                    \
    const float du_ = dl_ * u_;                                         \
    float yp_ = 0.f;                                                    \
    _Pragma("unroll") for (int j = 0; j < 24; ++j) {                    \
      const float e_ = __expf(dl_ * a[j]);                              \
      h[j] = fmaf(e_, h[j], du_ * Bv_[j]);                              \
      yp_ = fmaf(h[j], Cv_[j], yp_);                                    \
    }                                                                   \
    yg[(sl_ << 6) + d] = __float2bfloat16(yp_ + u_ * Dv);               \
  }

  KB_LOAD(0, uA, dA, BA, CA);
  for (int t = 0; t < 256; t += 2) {
    KB_LOAD(t + 1, uB, dB, BB, CB);
    KB_STEP(t, uA, dA, BA, CA);
    KB_LOAD(t + 2, uA, dA, BA, CA);
    KB_STEP(t + 1, uB, dB, BB, CB);
  }
#undef KB_LOAD
#undef KB_STEP
}

// ===========================================================================
// KC: merge (4 plain row reads) + LayerNorm + z-gate (recomputed) + out_proj.
// grid 256 = m*128+b, block 256 (thread = pixel p).
// ===========================================================================
__global__ __launch_bounds__(256) void kc_finish(KParams P) {
  const int bid = blockIdx.x;
  const int m = bid >> 7;
  const int p = threadIdx.x;
  const int pbm = 2 + 13 * m;
  const bf16* __restrict__ yb = P.ys + (bid << 2) * 16384;
  const uint* __restrict__ r0 = (const uint*)(yb + (p << 6));
  const uint* __restrict__ r1 = (const uint*)(yb + 16384 + (p << 6));
  const uint* __restrict__ r2 = (const uint*)(yb + 32768 + (p << 6));
  const uint* __restrict__ r3 = (const uint*)(yb + 49152 + (p << 6));
  float ym[64];
  float mu = 0.f;
#pragma unroll
  for (int j = 0; j < 32; ++j) {
    const uint a0 = r0[j], a1 = r1[j], a2 = r2[j], a3 = r3[j];
    const float e0 = bflo_(a0) + bflo_(a1) + bflo_(a2) + bflo_(a3);
    const float e1 = bfhi_(a0) + bfhi_(a1) + bfhi_(a2) + bfhi_(a3);
    ym[2 * j] = e0; ym[2 * j + 1] = e1;
    mu += e0 + e1;
  }
  mu *= (1.f / 64.f);
  float var = 0.f;
#pragma unroll
  for (int dd = 0; dd < 64; ++dd) { const float t = ym[dd] - mu; var = fmaf(t, t, var); }
  const float rstd = rsqrtf(var * (1.f / 64.f) + 1e-5f);

  // z = silu(x_in @ Win^T)
  const float* __restrict__ xin = P.in[m] + (((bid & 127) << 8) + p) * 64;
  const float* __restrict__ win = P.in[pbm];
  float zacc[64];
#pragma unroll
  for (int dd = 0; dd < 64; ++dd) zacc[dd] = 0.f;
  for (int c = 0; c < 64; ++c) {
    const float xv = xin[c];
#pragma unroll
    for (int dd = 0; dd < 64; ++dd) zacc[dd] = fmaf(xv, win[dd * 64 + c], zacc[dd]);
  }
  const float* __restrict__ lng = P.in[28];
  const float* __restrict__ lnb = P.in[29];
  float v[64];
#pragma unroll
  for (int dd = 0; dd < 64; ++dd) {
    const float yn = fmaf((ym[dd] - mu) * rstd, lng[dd], lnb[dd]);
    v[dd] = yn * silu_(zacc[dd]);
  }
  const float* __restrict__ wout = P.in[pbm + 12];
  float oacc[64];
#pragma unroll
  for (int o = 0; o < 64; ++o) oacc[o] = 0.f;
  for (int dd = 0; dd < 64; ++dd) {
    const float vv = v[dd];
#pragma unroll
    for (int o = 0; o < 64; ++o) oacc[o] = fmaf(vv, wout[o * 64 + dd], oacc[o]);
  }
  __shared__ float obuf[16640];
#pragma unroll
  for (int o = 0; o < 64; ++o) obuf[p * 65 + o] = oacc[o];
  __syncthreads();
  float* __restrict__ og = P.out + (bid << 14);
  for (int idx = p; idx < 4096; idx += 256) {
    const int pp = idx >> 4, q = (idx & 15) << 2;
    const float* ob = obuf + pp * 65 + q;
    ((float4*)og)[idx] = make_float4(ob[0], ob[1], ob[2], ob[3]);
  }
}

// ===========================================================================
extern "C" void kernel_launch(void* const* d_in, const int* in_sizes, int n_in,
                              void* d_out, int out_size, void* d_ws, size_t ws_size,
                              hipStream_t stream) {
  (void)in_sizes; (void)out_size;
  if (n_in < 30) return;
  if (ws_size < 125829120ull) return;
  KParams P;
  for (int i = 0; i < 30; ++i) P.in[i] = (const float*)d_in[i];
  char* w = (char*)d_ws;
  P.xld = (bf16*)(w);
  P.dts = (bf16*)(w + 8388608);
  P.Bs  = (float*)(w + 41943040);
  P.Cs  = (float*)(w + 67108864);
  P.ys  = (bf16*)(w + 92274688);
  P.out = (float*)d_out;
  hipLaunchKernelGGL(ka_front, dim3(256), dim3(512), 0, stream, P);
  hipLaunchKernelGGL(kp_proj, dim3(1024), dim3(256), 0, stream, P);
  hipLaunchKernelGGL(kb_scan, dim3(1024), dim3(64), 0, stream, P);
  hipLaunchKernelGGL(kc_finish, dim3(256), dim3(256), 0, stream, P);
}